// Round 15
// baseline (5448.246 us; speedup 1.0000x reference)
//
#include <hip/hip_runtime.h>

#define DEVI __device__ __forceinline__

typedef __attribute__((ext_vector_type(8))) __bf16 bf16x8;
typedef __attribute__((ext_vector_type(4))) float floatx4;

constexpr int Bsz = 8192;   // batch
constexpr int Hd  = 2048;   // hidden
constexpr int INd = 2048;   // input dim
constexpr int N1  = Bsz * INd;

DEVI unsigned short f2bf_rne(float f) {
  unsigned int u = __float_as_uint(f);
  u += 0x7FFFu + ((u >> 16) & 1u);
  return (unsigned short)(u >> 16);
}

__global__ void cvt4(const float* __restrict__ s0, const float* __restrict__ s1,
                     const float* __restrict__ s2, const float* __restrict__ s3,
                     unsigned short* __restrict__ dst) {
  const float* src = (blockIdx.y == 0) ? s0 : (blockIdx.y == 1) ? s1
                   : (blockIdx.y == 2) ? s2 : s3;
  unsigned short* out = dst + (size_t)blockIdx.y * N1;
  const int nv = N1 / 4;
  for (int i = blockIdx.x * blockDim.x + threadIdx.x; i < nv;
       i += gridDim.x * blockDim.x) {
    float4 v = ((const float4*)src)[i];
    ushort4 o;
    o.x = f2bf_rne(v.x); o.y = f2bf_rne(v.y);
    o.z = f2bf_rne(v.z); o.w = f2bf_rne(v.w);
    ((ushort4*)out)[i] = o;
  }
}

DEVI void gload_lds16(const void* g, void* l) {
  __builtin_amdgcn_global_load_lds(
      (const __attribute__((address_space(1))) void*)g,
      (__attribute__((address_space(3))) void*)l, 16, 0, 0);
}

DEVI float sigm(float x) { return 1.0f / (1.0f + __expf(-x)); }
DEVI float tanh_fast(float x) { return 1.0f - 2.0f / (1.0f + __expf(2.0f * x)); }

// R15: 256x256 tile (R11 geometry, low HBM traffic) with BK=32:
// LDS = 2buf x (A[256][32] + B[256][32]) bf16 = 64 KiB -> 2 BLOCKS/CU
// (R14's occupancy win without its traffic loss). 8 waves (2M x 4N),
// 16x16x32 MFMA, R9/R11 ring halved: 12 ds_read + 16x... 32 MFMA per
// K-tile(32) per wave... (8 MFMA x 4 clusters), 2 barriers/K-tile.
// With 64B row stride the fragment read (row*64 + lk*16) spreads over
// granule-classes (row&1)*4+lk = conflict-free LINEAR layout (no XOR,
// no source pre-swizzle). Single base ptr per operand; buffer parity
// folded into compile-time ds offsets (<= 44 KB). VGPR ~ acc64+frag48+
// addr ~= 115 < 128 (launch_bounds(512,4) budget).
// Depth-1 staging: tile t stages t+1 (4 gloads/wave, ph1-2), counted
// drain at ph4 (~550 cyc flight; 2nd block covers residual misses).
__global__ __launch_bounds__(512, 4) void lstm_gemm(
    const unsigned short* __restrict__ ws,
    const float* __restrict__ bias,
    const float* __restrict__ c_prev,
    float* __restrict__ out_h,
    float* __restrict__ out_c) {
  __shared__ __align__(16) unsigned short sm[2 * 2 * 256 * 32];  // 64 KiB
  char* smc = (char*)sm;

  const unsigned short* xb  = ws;
  const unsigned short* hb  = ws + (size_t)N1;
  const unsigned short* wih = ws + (size_t)2 * N1;
  const unsigned short* whh = ws + (size_t)3 * N1;

  const int tid  = threadIdx.x;
  const int lane = tid & 63;
  const int wid  = tid >> 6;
  const int wm   = wid >> 2, wn = wid & 3;   // R11 wave layout
  const int lr   = lane & 15, lk = lane >> 4;

  // XCD-aware chunked swizzle (R11: FETCH 1.1GB -> 427MB).
  const int wg = blockIdx.x;
  const int x8 = wg & 7;
  const int lc = wg >> 3;
  const int bc = (x8 & 3) * 8 + (lc & 7);             // h-col tile 0..31
  const int rb = ((x8 >> 2) * 16 + (lc >> 3)) * 256;  // batch row base

  // Staging source offsets (elements), K-tile-independent. Wave wid stages
  // LDS rows [wid*32, wid*32+32) as 2 gloads of 16 rows; lane l -> row
  // +(l>>2), chunk l&3 (linear; no swizzle needed at BK=32).
  unsigned int aOff[2], bOff[2];
#pragma unroll
  for (int j = 0; j < 2; ++j) {
    const int r = wid * 32 + j * 16 + (lane >> 2);
    aOff[j] = (unsigned)(rb + r) * 2048u + (unsigned)((lane & 3) * 8);
    const int cf = r >> 4, ce = r & 15;                 // R11 B mapping
    const int gate = (cf & 1) | ((cf >> 2) & 2);
    const int hch  = (cf >> 1) & 3;
    const int wrow = gate * 2048 + bc * 64 + hch * 16 + ce;
    bOff[j] = (unsigned)wrow * 2048u + (unsigned)((lane & 3) * 8);
  }

  // Per-lane LDS read bases (linear, loop-invariant). Per buf: A 16K @ +0,
  // B 16K @ +16384; buf stride 32768 folded into compile-time offsets.
  const char* pA = smc + wm * 4096 + lr * 64 + lk * 16;          // A row wm*64+..: (qm*128+wm*64+mr*16+lr)*64
  const char* pB = smc + 16384 + wn * 2048 + lr * 64 + lk * 16;  // B row (qn*8+wn*2+nc)*16+lr

  floatx4 acc[2][4][2][2];
#pragma unroll
  for (int a = 0; a < 2; ++a)
#pragma unroll
    for (int b = 0; b < 4; ++b)
#pragma unroll
      for (int c = 0; c < 2; ++c)
#pragma unroll
        for (int d = 0; d < 2; ++d)
          acc[a][b][c][d] = (floatx4){0.f, 0.f, 0.f, 0.f};

#define STAGE_A(ts) {                                                         \
    const int p_ = (ts) & 1;                                                  \
    const unsigned short* s_ = (((ts) < 64) ? xb : hb) + (((ts) & 63) * 32);  \
    gload_lds16(s_ + aOff[0], smc + p_ * 32768 + wid * 2048);                 \
    gload_lds16(s_ + aOff[1], smc + p_ * 32768 + wid * 2048 + 1024); }
#define STAGE_B(ts) {                                                         \
    const int p_ = (ts) & 1;                                                  \
    const unsigned short* s_ = (((ts) < 64) ? wih : whh) + (((ts) & 63) * 32);\
    gload_lds16(s_ + bOff[0], smc + p_ * 32768 + 16384 + wid * 2048);         \
    gload_lds16(s_ + bOff[1], smc + p_ * 32768 + 16384 + wid * 2048 + 1024); }

// Fragment reads: base + compile-time offset only.
// A byte: P*32768 + qm*8192 + mr*1024 (row = qm*128+wm*64+mr*16+lr).
// B byte: P*32768 + qn*8192 + nc*1024 (row = (qn*8+wn*2+nc)*16+lr).
#define LDA(D, P, QM)                                                         \
  _Pragma("unroll") for (int mr = 0; mr < 4; ++mr)                            \
    D[mr] = *(const bf16x8*)(pA + ((P) * 32768 + (QM) * 8192 + mr * 1024));
#define LDB(D, P, QN)                                                         \
  _Pragma("unroll") for (int nc = 0; nc < 2; ++nc)                            \
    D[nc] = *(const bf16x8*)(pB + ((P) * 32768 + (QN) * 8192 + nc * 1024));
#define MM8(QM, QN, AF, BG)                                                   \
  __builtin_amdgcn_s_setprio(1);                                              \
  _Pragma("unroll") for (int mr = 0; mr < 4; ++mr)                            \
    _Pragma("unroll") for (int nc = 0; nc < 2; ++nc)                          \
      acc[QM][mr][QN][nc] = __builtin_amdgcn_mfma_f32_16x16x32_bf16(          \
          AF[mr], BG[nc], acc[QM][mr][QN][nc], 0, 0, 0);                      \
  __builtin_amdgcn_s_setprio(0);
#define BAR  asm volatile("s_barrier" ::: "memory")
#define VM0  asm volatile("s_waitcnt vmcnt(0)" ::: "memory")
#define NOP  (void)0

// One K-tile(32), buf P, ring (0,0)(1,0)(1,1)(0,1), 2 barriers.
// Reads: ph1 A0(4)+B0(2); ph2 A1(4); ph3 B1(2); ph4 none (register holds).
// Stages t+1 into buf P^1 at ph1/ph2 (WAR: P^1's last reads lgkm-consumed
// before t-1's end-BAR); counted drain W at ph4 after the final
// register-only MFMA cluster (RAW for tile t+1), then BAR.
#define KTILE(P, SA, SB, W) {                                                 \
    bf16x8 afA[4], afB[4], bg0[2], bg1[2];                                    \
    LDA(afA, P, 0); LDB(bg0, P, 0); SA;                                       \
    MM8(0, 0, afA, bg0);                                                      \
    LDA(afB, P, 1); SB;                                                       \
    MM8(1, 0, afB, bg0); BAR;                                                 \
    LDB(bg1, P, 1);                                                           \
    MM8(1, 1, afB, bg1);                                                      \
    MM8(0, 1, afA, bg1); W; BAR;                                              \
  }

  // Prologue: stage tile 0, drain, barrier.
  STAGE_A(0); STAGE_B(0);
  VM0;
  BAR;

  // 128 K-tiles of 32 (64 from x/W_ih, 64 from h/W_hh), unrolled x2.
  for (int u = 0; u < 63; ++u) {
    const int t0 = 2 * u;
    KTILE(0, STAGE_A(t0 + 1), STAGE_B(t0 + 1), VM0);
    KTILE(1, STAGE_A(t0 + 2), STAGE_B(t0 + 2), VM0);
  }
  KTILE(0, STAGE_A(127), STAGE_B(127), VM0);  // t = 126
  KTILE(1, NOP, NOP, NOP);                    // t = 127

  // Epilogue: lane-local LSTM (R11-verified mapping, unchanged).
  const int hcol = bc * 64 + wn * 16 + lr;
  const float b_i = bias[hcol];
  const float b_f = bias[2048 + hcol];
  const float b_j = bias[4096 + hcol];
  const float b_o = bias[6144 + hcol];
#pragma unroll
  for (int qm = 0; qm < 2; ++qm)
#pragma unroll
    for (int mr = 0; mr < 4; ++mr)
#pragma unroll
      for (int r = 0; r < 4; ++r) {
        const int row = rb + qm * 128 + wm * 64 + mr * 16 + lk * 4 + r;
        const float gi = acc[qm][mr][0][0][r] + b_i;
        const float gf = acc[qm][mr][0][1][r] + b_f;
        const float gj = acc[qm][mr][1][0][r] + b_j;
        const float go = acc[qm][mr][1][1][r] + b_o;
        const float iv = sigm(gi);
        const float fv = sigm(gf);
        const float jv = tanh_fast(gj);
        const float ov = sigm(go);
        const size_t idx = (size_t)row * 2048 + hcol;
        const float cp = c_prev[idx];
        const float cv = fv * cp + fminf(1.0f - fv, iv) * jv;
        out_h[idx] = ov * tanh_fast(cv);
        out_c[idx] = cv;
      }
}

extern "C" void kernel_launch(void* const* d_in, const int* in_sizes, int n_in,
                              void* d_out, int out_size, void* d_ws, size_t ws_size,
                              hipStream_t stream) {
  const float* x      = (const float*)d_in[0];
  const float* h_prev = (const float*)d_in[1];
  const float* c_prev = (const float*)d_in[2];
  const float* w_ih   = (const float*)d_in[3];
  const float* w_hh   = (const float*)d_in[4];
  const float* bias   = (const float*)d_in[5];

  float* out_h = (float*)d_out;
  float* out_c = out_h + (size_t)Bsz * Hd;
  unsigned short* wsb = (unsigned short*)d_ws;

  dim3 cgrid(2048, 4);
  cvt4<<<cgrid, 256, 0, stream>>>(x, h_prev, w_ih, w_hh, wsb);

  lstm_gemm<<<1024, 512, 0, stream>>>(wsb, bias, c_prev, out_h, out_c);
}

// Round 16
// 618.879 us; speedup vs baseline: 8.8034x; 8.8034x over previous
//
#include <hip/hip_runtime.h>

#define DEVI __device__ __forceinline__

typedef __attribute__((ext_vector_type(8))) __bf16 bf16x8;
typedef __attribute__((ext_vector_type(4))) float floatx4;

constexpr int Bsz = 8192;   // batch
constexpr int Hd  = 2048;   // hidden
constexpr int INd = 2048;   // input dim
constexpr int N1  = Bsz * INd;

DEVI unsigned short f2bf_rne(float f) {
  unsigned int u = __float_as_uint(f);
  u += 0x7FFFu + ((u >> 16) & 1u);
  return (unsigned short)(u >> 16);
}

__global__ void cvt4(const float* __restrict__ s0, const float* __restrict__ s1,
                     const float* __restrict__ s2, const float* __restrict__ s3,
                     unsigned short* __restrict__ dst) {
  const float* src = (blockIdx.y == 0) ? s0 : (blockIdx.y == 1) ? s1
                   : (blockIdx.y == 2) ? s2 : s3;
  unsigned short* out = dst + (size_t)blockIdx.y * N1;
  const int nv = N1 / 4;
  for (int i = blockIdx.x * blockDim.x + threadIdx.x; i < nv;
       i += gridDim.x * blockDim.x) {
    float4 v = ((const float4*)src)[i];
    ushort4 o;
    o.x = f2bf_rne(v.x); o.y = f2bf_rne(v.y);
    o.z = f2bf_rne(v.z); o.w = f2bf_rne(v.w);
    ((ushort4*)out)[i] = o;
  }
}

DEVI void gload_lds16(const void* g, void* l) {
  __builtin_amdgcn_global_load_lds(
      (const __attribute__((address_space(1))) void*)g,
      (__attribute__((address_space(3))) void*)l, 16, 0, 0);
}

DEVI float sigm(float x) { return 1.0f / (1.0f + __expf(-x)); }
DEVI float tanh_fast(float x) { return 1.0f - 2.0f / (1.0f + __expf(2.0f * x)); }

// R16: 256(batch) x 128(4 gates x 32 h-cols) tile, BK=32, 8 waves (4M x 2N),
// 16x16x32 MFMA. acc = 256*128/512 = 64 VGPR (fits 2-blk/CU budget, unlike
// 256^2 whose acc alone is 128). LDS = 2buf x (A 16K + B 8K) = 48 KiB ->
// 2 BLOCKS/CU. Depth-2 counted pipeline (fixes R14's depth-1 vmcnt(0)):
//   per tile t: ph1 stage B(t+1)->P^1 (1 gload); ph3 stage A(t+2)->P
//   (2 gloads; A-P last read ph2, mid-BAR separates -> WAR-safe);
//   ph4 vmcnt(2) = drains A(t+1)+B(t+1), leaves A(t+2) in flight.
// Ring (QM,QN) = (0,0)(1,0)(1,1)(0,1), register holds, 8 ds_read +
// 16 MFMA per K-tile(32), 2 barriers. Linear LDS (64B rows): frag read
// covers all 32 banks at 32B/bank -> conflict-free, no XOR.
// B col cf = wn*4 + gate -> gate = ni (lane-local), h-col = bc*32+wn*16+lr.
__global__ __launch_bounds__(512, 4) void lstm_gemm(
    const unsigned short* __restrict__ ws,
    const float* __restrict__ bias,
    const float* __restrict__ c_prev,
    float* __restrict__ out_h,
    float* __restrict__ out_c) {
  __shared__ __align__(16) unsigned short sm[2 * (256 + 128) * 32];  // 48 KiB
  char* smc = (char*)sm;

  const unsigned short* xb  = ws;
  const unsigned short* hb  = ws + (size_t)N1;
  const unsigned short* wih = ws + (size_t)2 * N1;
  const unsigned short* whh = ws + (size_t)3 * N1;

  const int tid  = threadIdx.x;
  const int lane = tid & 63;
  const int wid  = tid >> 6;
  const int wm   = wid >> 1;    // M wave 0..3 (64 rows)
  const int wn   = wid & 1;     // N wave 0..1 (64 cols = 4 gates x 16 h)
  const int lr   = lane & 15, lk = lane >> 4;

  // XCD-aware chunked swizzle: 2048 blocks = 8 XCDs x 256 (16M x 16N chunk).
  const int wg = blockIdx.x;
  const int x8 = wg & 7;
  const int lc = wg >> 3;                               // 0..255
  const int bc = (x8 & 3) * 16 + (lc & 15);             // h-panel 0..63 (32 h-cols)
  const int rb = ((x8 >> 2) * 16 + (lc >> 4)) * 256;    // batch row base

  // Staging source offsets (elements). Lane l -> row +(l>>2), chunk l&3.
  // A: wave stages LDS rows [wid*32, wid*32+32) (2 gloads of 16 rows).
  // B: wave stages LDS rows [wid*16, wid*16+16) (1 gload).
  unsigned int aOff[2], bOff;
#pragma unroll
  for (int j = 0; j < 2; ++j) {
    const int r = wid * 32 + j * 16 + (lane >> 2);
    aOff[j] = (unsigned)(rb + r) * 2048u + (unsigned)((lane & 3) * 8);
  }
  {
    const int r = wid * 16 + (lane >> 2);               // B LDS row 0..127
    const int gate = (r >> 4) & 3, wnn = r >> 6;
    const int wrow = gate * 2048 + bc * 32 + wnn * 16 + (r & 15);
    bOff = (unsigned)wrow * 2048u + (unsigned)((lane & 3) * 8);
  }

  // LDS layout per buf P: A @ P*16384 (16 KB of 32 KB total A);  B @ 32768 +
  // P*8192. Read bases (linear, loop-invariant):
  const char* pA = smc + wm * 4096 + lr * 64 + lk * 16;          // + P*16384 + mf*1024
  const char* pB = smc + 32768 + wn * 4096 + lr * 64 + lk * 16;  // + P*8192 + ni*1024

  floatx4 acc[4][4];  // [mf][ni = gate]
#pragma unroll
  for (int a = 0; a < 4; ++a)
#pragma unroll
    for (int b = 0; b < 4; ++b)
      acc[a][b] = (floatx4){0.f, 0.f, 0.f, 0.f};

#define STAGE_A(ts) {                                                         \
    const int p_ = (ts) & 1;                                                  \
    const unsigned short* s_ = (((ts) < 64) ? xb : hb) + (((ts) & 63) * 32);  \
    gload_lds16(s_ + aOff[0], smc + p_ * 16384 + wid * 2048);                 \
    gload_lds16(s_ + aOff[1], smc + p_ * 16384 + wid * 2048 + 1024); }
#define STAGE_B(ts) {                                                         \
    const int p_ = (ts) & 1;                                                  \
    const unsigned short* s_ = (((ts) < 64) ? wih : whh) + (((ts) & 63) * 32);\
    gload_lds16(s_ + bOff, smc + 32768 + p_ * 8192 + wid * 1024); }

// Fragment reads: base + compile-time offset. A row = wm*64 + mf*16 + lr;
// B row = wn*64 + ni*16 + lr (ni = gate).
#define LDA2(D, P, QM)                                                        \
  _Pragma("unroll") for (int m = 0; m < 2; ++m)                               \
    D[m] = *(const bf16x8*)(pA + ((P) * 16384 + ((QM) * 2 + m) * 1024));
#define LDB2(D, P, QN)                                                        \
  _Pragma("unroll") for (int n = 0; n < 2; ++n)                               \
    D[n] = *(const bf16x8*)(pB + ((P) * 8192 + ((QN) * 2 + n) * 1024));
#define MM4(AF, BF, QM, QN)                                                   \
  __builtin_amdgcn_s_setprio(1);                                              \
  _Pragma("unroll") for (int m = 0; m < 2; ++m)                               \
    _Pragma("unroll") for (int n = 0; n < 2; ++n)                             \
      acc[(QM) * 2 + m][(QN) * 2 + n] =                                       \
          __builtin_amdgcn_mfma_f32_16x16x32_bf16(                            \
              AF[m], BF[n], acc[(QM) * 2 + m][(QN) * 2 + n], 0, 0, 0);        \
  __builtin_amdgcn_s_setprio(0);
#define BAR  asm volatile("s_barrier" ::: "memory")
#define VM2  asm volatile("s_waitcnt vmcnt(2)" ::: "memory")
#define VM0  asm volatile("s_waitcnt vmcnt(0)" ::: "memory")
#define NOP  (void)0

// One K-tile(32), buf P, 2 barriers.
// Reads: ph1 A0(2)+B0(2); ph2 A1(2); ph3 B1(2); ph4 none (holds).
// Stages: S1 = B(t+1)->P^1 at ph1 (P^1's B last read tile t-1 ph3, behind
// end-BAR); S3 = A(t+2)->P at ph3 (A-P last read ph2, behind mid-BAR).
// W at ph4 after the register-only MFMA cluster, then end-BAR.
#define KTILE(P, S1, S3, W) {                                                 \
    bf16x8 a0[2], a1[2], b0[2], b1[2];                                        \
    LDA2(a0, P, 0); LDB2(b0, P, 0); S1;                                       \
    MM4(a0, b0, 0, 0);                                                        \
    LDA2(a1, P, 1);                                                           \
    MM4(a1, b0, 1, 0); BAR;                                                   \
    LDB2(b1, P, 1); S3;                                                       \
    MM4(a1, b1, 1, 1);                                                        \
    MM4(a0, b1, 0, 1); W; BAR;                                                \
  }

  // Prologue: stage A0,B0 (tile 0) + A1 (depth-2 A); drain; barrier.
  STAGE_A(0); STAGE_B(0); STAGE_A(1);
  VM0;
  BAR;

  // 128 K-tiles of 32 (64 x/W_ih + 64 h/W_hh), unrolled x2.
  for (int u = 0; u < 63; ++u) {
    const int t0 = 2 * u;
    KTILE(0, STAGE_B(t0 + 1), STAGE_A(t0 + 2), VM2);
    KTILE(1, STAGE_B(t0 + 2), STAGE_A(t0 + 3), VM2);
  }
  KTILE(0, STAGE_B(127), NOP, VM0);  // t = 126: last B; drain all
  KTILE(1, NOP, NOP, NOP);           // t = 127

  // Epilogue: gate = ni (lane-local).
  const int hcol = bc * 32 + wn * 16 + lr;
  const float b_i = bias[hcol];
  const float b_f = bias[2048 + hcol];
  const float b_j = bias[4096 + hcol];
  const float b_o = bias[6144 + hcol];
#pragma unroll
  for (int mf = 0; mf < 4; ++mf)
#pragma unroll
    for (int r = 0; r < 4; ++r) {
      const int row = rb + wm * 64 + mf * 16 + lk * 4 + r;
      const float gi = acc[mf][0][r] + b_i;
      const float gf = acc[mf][1][r] + b_f;
      const float gj = acc[mf][2][r] + b_j;
      const float go = acc[mf][3][r] + b_o;
      const float iv = sigm(gi);
      const float fv = sigm(gf);
      const float jv = tanh_fast(gj);
      const float ov = sigm(go);
      const size_t idx = (size_t)row * 2048 + hcol;
      const float cp = c_prev[idx];
      const float cv = fv * cp + fminf(1.0f - fv, iv) * jv;
      out_h[idx] = ov * tanh_fast(cv);
      out_c[idx] = cv;
    }
}

extern "C" void kernel_launch(void* const* d_in, const int* in_sizes, int n_in,
                              void* d_out, int out_size, void* d_ws, size_t ws_size,
                              hipStream_t stream) {
  const float* x      = (const float*)d_in[0];
  const float* h_prev = (const float*)d_in[1];
  const float* c_prev = (const float*)d_in[2];
  const float* w_ih   = (const float*)d_in[3];
  const float* w_hh   = (const float*)d_in[4];
  const float* bias   = (const float*)d_in[5];

  float* out_h = (float*)d_out;
  float* out_c = out_h + (size_t)Bsz * Hd;
  unsigned short* wsb = (unsigned short*)d_ws;

  dim3 cgrid(2048, 4);
  cvt4<<<cgrid, 256, 0, stream>>>(x, h_prev, w_ih, w_hh, wsb);

  // (8192/256) M-panels x (2048/32) h-panels = 32 x 64 = 2048 blocks.
  lstm_gemm<<<2048, 512, 0, stream>>>(wsb, bias, c_prev, out_h, out_c);
}

// Round 17
// 517.302 us; speedup vs baseline: 10.5320x; 1.1964x over previous
//
#include <hip/hip_runtime.h>

#define DEVI __device__ __forceinline__

typedef __attribute__((ext_vector_type(8))) __bf16 bf16x8;
typedef __attribute__((ext_vector_type(4))) float floatx4;

constexpr int Bsz = 8192;   // batch
constexpr int Hd  = 2048;   // hidden
constexpr int INd = 2048;   // input dim
constexpr int N1  = Bsz * INd;

DEVI unsigned short f2bf_rne(float f) {
  unsigned int u = __float_as_uint(f);
  u += 0x7FFFu + ((u >> 16) & 1u);
  return (unsigned short)(u >> 16);
}

__global__ void cvt4(const float* __restrict__ s0, const float* __restrict__ s1,
                     const float* __restrict__ s2, const float* __restrict__ s3,
                     unsigned short* __restrict__ dst) {
  const float* src = (blockIdx.y == 0) ? s0 : (blockIdx.y == 1) ? s1
                   : (blockIdx.y == 2) ? s2 : s3;
  unsigned short* out = dst + (size_t)blockIdx.y * N1;
  const int nv = N1 / 4;
  for (int i = blockIdx.x * blockDim.x + threadIdx.x; i < nv;
       i += gridDim.x * blockDim.x) {
    float4 v = ((const float4*)src)[i];
    ushort4 o;
    o.x = f2bf_rne(v.x); o.y = f2bf_rne(v.y);
    o.z = f2bf_rne(v.z); o.w = f2bf_rne(v.w);
    ((ushort4*)out)[i] = o;
  }
}

DEVI void gload_lds16(const void* g, void* l) {
  __builtin_amdgcn_global_load_lds(
      (const __attribute__((address_space(1))) void*)g,
      (__attribute__((address_space(3))) void*)l, 16, 0, 0);
}

DEVI float sigm(float x) { return 1.0f / (1.0f + __expf(-x)); }
DEVI float tanh_fast(float x) { return 1.0f - 2.0f / (1.0f + __expf(2.0f * x)); }

// R17: R11 geometry (256x256 tile, BK=64, 128 KiB LDS, 0-conflict XOR
// swizzle, precomputed read bases, 427 MB FETCH) with SIXTEEN waves
// (1024 threads, 4M x 4N) -> 4 waves/SIMD instead of 2. Between barriers,
// 4 waves hide ds_read latency / MFMA issue gaps that 2 could not.
// acc = 256*256/1024 = 64 VGPR; frags 32; bases ~15 -> ~120 <= 128 budget
// (launch_bounds(1024,4)). Per wave per K-tile: 16 ds_read_b128, 32 MFMA,
// 4 gloads. Schedule = R16's hazard-proven ledger on R11's 2-barrier ring:
//   ph1: read a01,b01; stage B(t+1)->P^1; MFMA(0,0)
//   ph2: read a23;                        MFMA(1,0)   [mid-BAR]
//   ph3: read b23;     stage A(t+2)->P;   MFMA(1,1)
//   ph4:                                  MFMA(0,1); vmcnt(2) [end-BAR]
// WAR: A-P last read ph2 (lgkm-consumed pre-mid-BAR) -> ph3 stage safe;
// B-P^1 last read t-1 ph3 (pre t-1 end-BAR) -> ph1 stage safe.
// vmcnt(2) drains B(t+1)+A(t+1) (t+1 fully staged), leaves A(t+2) flying.
__global__ __launch_bounds__(1024, 4) void lstm_gemm(
    const unsigned short* __restrict__ ws,
    const float* __restrict__ bias,
    const float* __restrict__ c_prev,
    float* __restrict__ out_h,
    float* __restrict__ out_c) {
  __shared__ __align__(16) unsigned short sm[4 * 256 * 64];  // 128 KiB
  char* smc = (char*)sm;

  const unsigned short* xb  = ws;
  const unsigned short* hb  = ws + (size_t)N1;
  const unsigned short* wih = ws + (size_t)2 * N1;
  const unsigned short* whh = ws + (size_t)3 * N1;

  const int tid  = threadIdx.x;
  const int lane = tid & 63;
  const int wid  = tid >> 6;    // 0..15
  const int wm   = wid >> 2;    // M wave 0..3 (64 rows)
  const int wn   = wid & 3;     // N wave 0..3 (64 cols = 4 gates x 16 h)
  const int lr   = lane & 15, lk = lane >> 4;
  const int lr8  = lane >> 3;
  const int swc  = ((lane & 7) ^ lr8) * 8;   // pre-swizzled source chunk

  // XCD-aware chunked swizzle (R11: FETCH 1.1GB -> 427MB). 1024 blocks.
  const int wg = blockIdx.x;
  const int x8 = wg & 7;
  const int lc = wg >> 3;
  const int bc = (x8 & 3) * 8 + (lc & 7);             // h-panel 0..31
  const int rb = ((x8 >> 2) * 16 + (lc >> 3)) * 256;  // batch row base

  // Staging source offsets (elements). Wave wid stages LDS rows
  // [wid*16, +16) as two 8-row gloads; lane l -> row +(l>>3).
  unsigned int aOff[2], bOff[2];
#pragma unroll
  for (int j = 0; j < 2; ++j) {
    const int r = wid * 16 + j * 8 + lr8;     // LDS row 0..255
    aOff[j] = (unsigned)(rb + r) * 2048u + (unsigned)swc;
    // B LDS row c -> weight row: gate=(c>>4)&3, hch=c>>6, ce=c&15.
    const int wrow = ((r >> 4) & 3) * 2048 + bc * 64 + (r >> 6) * 16 + (r & 15);
    bOff[j] = (unsigned)wrow * 2048u + (unsigned)swc;
  }

  // Precomputed per-lane LDS read bases; P and frag index fold into
  // compile-time ds offsets (max 32768 + 6144 < 65536).
  const char* pA[2];
  const char* pB[2];
#pragma unroll
  for (int s = 0; s < 2; ++s) {
    const int phys = (s * 4 + lk) ^ (lr & 7);
    pA[s] = smc + wm * 8192 + lr * 128 + phys * 16;
    pB[s] = smc + 65536 + wn * 8192 + lr * 128 + phys * 16;
  }

  floatx4 acc[4][4];  // [mf][nf = gate]
#pragma unroll
  for (int a = 0; a < 4; ++a)
#pragma unroll
    for (int b = 0; b < 4; ++b)
      acc[a][b] = (floatx4){0.f, 0.f, 0.f, 0.f};

#define STAGE_A(ts) {                                                         \
    const int p_ = (ts) & 1;                                                  \
    const unsigned short* s_ = (((ts) < 32) ? xb : hb) + (((ts) & 31) * 64);  \
    gload_lds16(s_ + aOff[0], smc + p_ * 32768 + wid * 2048);                 \
    gload_lds16(s_ + aOff[1], smc + p_ * 32768 + wid * 2048 + 1024); }
#define STAGE_B(ts) {                                                         \
    const int p_ = (ts) & 1;                                                  \
    const unsigned short* s_ = (((ts) < 32) ? wih : whh) + (((ts) & 31) * 64);\
    gload_lds16(s_ + bOff[0], smc + 65536 + p_ * 32768 + wid * 2048);         \
    gload_lds16(s_ + bOff[1], smc + 65536 + p_ * 32768 + wid * 2048 + 1024); }

// Fragment reads: base + compile-time offset. A row = wm*64 + mf*16 + lr
// (byte wm*8192 + mf*2048 + ...); B row = wn*64 + nf*16 + lr.
#define LDA2(D, P, QH)                                                        \
  _Pragma("unroll") for (int m = 0; m < 2; ++m)                               \
    _Pragma("unroll") for (int s = 0; s < 2; ++s)                             \
      D[m][s] = *(const bf16x8*)(pA[s] + ((P) * 32768 + ((QH) * 2 + m) * 2048));
#define LDB2(D, P, QH)                                                        \
  _Pragma("unroll") for (int n = 0; n < 2; ++n)                               \
    _Pragma("unroll") for (int s = 0; s < 2; ++s)                             \
      D[n][s] = *(const bf16x8*)(pB[s] + ((P) * 32768 + ((QH) * 2 + n) * 2048));
#define MFMA8(AF, BF, QM, QN)                                                 \
  __builtin_amdgcn_s_setprio(1);                                              \
  _Pragma("unroll") for (int m = 0; m < 2; ++m)                               \
    _Pragma("unroll") for (int n = 0; n < 2; ++n)                             \
      _Pragma("unroll") for (int s = 0; s < 2; ++s)                           \
        acc[(QM) * 2 + m][(QN) * 2 + n] =                                     \
            __builtin_amdgcn_mfma_f32_16x16x32_bf16(                          \
                AF[m][s], BF[n][s], acc[(QM) * 2 + m][(QN) * 2 + n], 0, 0, 0);\
  __builtin_amdgcn_s_setprio(0);
#define BAR  asm volatile("s_barrier" ::: "memory")
#define VM2  asm volatile("s_waitcnt vmcnt(2)" ::: "memory")
#define VM0  asm volatile("s_waitcnt vmcnt(0)" ::: "memory")
#define NOP  (void)0

#define KTILE(P, S1, S3, W) {                                                 \
    bf16x8 a01[2][2], a23[2][2], b01[2][2], b23[2][2];                        \
    LDA2(a01, P, 0); LDB2(b01, P, 0); S1;                                     \
    MFMA8(a01, b01, 0, 0);                                                    \
    LDA2(a23, P, 1);                                                          \
    MFMA8(a23, b01, 1, 0); BAR;                                               \
    LDB2(b23, P, 1); S3;                                                      \
    MFMA8(a23, b23, 1, 1);                                                    \
    MFMA8(a01, b23, 0, 1); W; BAR;                                            \
  }

  // Prologue: tile 0 (A+B) + depth-2 A(1); drain; barrier.
  STAGE_A(0); STAGE_B(0); STAGE_A(1);
  VM0;
  BAR;

  // 64 K-tiles of 64 (32 x/W_ih + 32 h/W_hh), unrolled x2.
  for (int u = 0; u < 31; ++u) {
    const int t0 = 2 * u;
    KTILE(0, STAGE_B(t0 + 1), STAGE_A(t0 + 2), VM2);
    KTILE(1, STAGE_B(t0 + 2), STAGE_A(t0 + 3), VM2);
  }
  KTILE(0, STAGE_B(63), NOP, VM0);  // t = 62: last B; full drain
  KTILE(1, NOP, NOP, NOP);          // t = 63

  // Epilogue: gate = nf (lane-local).
  const int hcol = bc * 64 + wn * 16 + lr;
  const float b_i = bias[hcol];
  const float b_f = bias[2048 + hcol];
  const float b_j = bias[4096 + hcol];
  const float b_o = bias[6144 + hcol];
#pragma unroll
  for (int mf = 0; mf < 4; ++mf)
#pragma unroll
    for (int r = 0; r < 4; ++r) {
      const int row = rb + wm * 64 + mf * 16 + lk * 4 + r;
      const float gi = acc[mf][0][r] + b_i;
      const float gf = acc[mf][1][r] + b_f;
      const float gj = acc[mf][2][r] + b_j;
      const float go = acc[mf][3][r] + b_o;
      const float iv = sigm(gi);
      const float fv = sigm(gf);
      const float jv = tanh_fast(gj);
      const float ov = sigm(go);
      const size_t idx = (size_t)row * 2048 + hcol;
      const float cp = c_prev[idx];
      const float cv = fv * cp + fminf(1.0f - fv, iv) * jv;
      out_h[idx] = ov * tanh_fast(cv);
      out_c[idx] = cv;
    }
}

extern "C" void kernel_launch(void* const* d_in, const int* in_sizes, int n_in,
                              void* d_out, int out_size, void* d_ws, size_t ws_size,
                              hipStream_t stream) {
  const float* x      = (const float*)d_in[0];
  const float* h_prev = (const float*)d_in[1];
  const float* c_prev = (const float*)d_in[2];
  const float* w_ih   = (const float*)d_in[3];
  const float* w_hh   = (const float*)d_in[4];
  const float* bias   = (const float*)d_in[5];

  float* out_h = (float*)d_out;
  float* out_c = out_h + (size_t)Bsz * Hd;
  unsigned short* wsb = (unsigned short*)d_ws;

  dim3 cgrid(2048, 4);
  cvt4<<<cgrid, 256, 0, stream>>>(x, h_prev, w_ih, w_hh, wsb);

  // 32 row-panels x 32 col-panels = 1024 blocks, 1024 threads (16 waves).
  lstm_gemm<<<1024, 1024, 0, stream>>>(wsb, bias, c_prev, out_h, out_c);
}